// Round 15
// baseline (212.269 us; speedup 1.0000x reference)
//
#include <hip/hip_runtime.h>
#include <math.h>
#include <stdint.h>

#define B_ 2
#define N_ 8192
#define D_ 64
#define K_ 10
#define CSPLIT 8                 // candidate-axis split
#define CAND_PB (N_ / CSPLIT)    // 1024 candidates per block
#define TILE_M 64                // candidates per chunk
#define NCH (CAND_PB / TILE_M)   // 16 chunks (pass 2)
#define SCH 4                    // pass-1 sample chunks (256 cands)
#define ROWS_PB 128              // 4 waves x 32 rows
#define C_ 16                    // per-lane survivor-stack capacity
#define NBK 16                   // pass-1 buckets
#define INF_ 3.4e38f

typedef __attribute__((ext_vector_type(8))) short bf16x8;
typedef __attribute__((ext_vector_type(16))) float f32x16;

// Async global->LDS DMA. LDS dest = wave-uniform base + lane*size (HW);
// global src is per-lane.
__device__ __forceinline__ void glds16(const void* g, void* l) {
    __builtin_amdgcn_global_load_lds(
        (const __attribute__((address_space(1))) unsigned int*)(uintptr_t)g,
        (__attribute__((address_space(3))) unsigned int*)(uint32_t)(uintptr_t)l,
        16, 0, 0);
}
__device__ __forceinline__ void glds4(const void* g, void* l) {
    __builtin_amdgcn_global_load_lds(
        (const __attribute__((address_space(1))) unsigned int*)(uintptr_t)g,
        (__attribute__((address_space(3))) unsigned int*)(uint32_t)(uintptr_t)l,
        4, 0, 0);
}

__device__ __forceinline__ uint32_t rne_bf16(float f) {
    uint32_t u = __float_as_uint(f);
    return ((u + 0x7FFFu + ((u >> 16) & 1u)) >> 16) & 0xFFFFu;
}

// ---------------------------------------------------------------------------
// Prep: f32 -> bf16 (RNE) with XOR slot-swizzle baked into the global layout;
// norm-extension rows Na (A-side: [-.5sq_hi, -.5sq_lo, 1, 1, 0..]) and
// Nb (B-side: [1, 1, -.5sq_hi, -.5sq_lo, 0..]), 16 halves each.
// Also zeroes the 129 completion counters (128 rowgroup + 1 final).
// ---------------------------------------------------------------------------
__global__ __launch_bounds__(256) void prep_kernel(const float* __restrict__ X,
                                                   uint16_t* __restrict__ Xsw,
                                                   uint16_t* __restrict__ Na,
                                                   uint16_t* __restrict__ Nb,
                                                   int* __restrict__ counters) {
    const int id = blockIdx.x * 256 + threadIdx.x;   // 0 .. B*N*8-1
    if (id < 129) counters[id] = 0;
    const int p = id >> 3;                           // global point
    const int slot = id & 7;
    const float4* s4 = (const float4*)(X + (size_t)p * D_ + slot * 8);
    float4 va = s4[0], vb = s4[1];
    float v[8] = {va.x, va.y, va.z, va.w, vb.x, vb.y, vb.z, vb.w};
    uint32_t h[8];
    float ss = 0.f;
#pragma unroll
    for (int i = 0; i < 8; ++i) {
        uint32_t u = __float_as_uint(v[i]);
        uint32_t r = (u + 0x7FFFu + ((u >> 16) & 1u)) & 0xFFFF0000u;  // RNE
        h[i] = r >> 16;
        float rv = __uint_as_float(r);
        ss = fmaf(rv, rv, ss);
    }
    uint4 w;
    w.x = h[0] | (h[1] << 16);
    w.y = h[2] | (h[3] << 16);
    w.z = h[4] | (h[5] << 16);
    w.w = h[6] | (h[7] << 16);
    *(uint4*)(Xsw + (size_t)p * D_ + (size_t)((slot ^ (p & 7)) * 8)) = w;
    ss += __shfl_xor(ss, 1);
    ss += __shfl_xor(ss, 2);
    ss += __shfl_xor(ss, 4);

    const float hv = -0.5f * ss;
    const uint32_t bh = rne_bf16(hv);
    const float rem = hv - __uint_as_float(bh << 16);
    const uint32_t bl = rne_bf16(rem);
    const uint32_t packn = bh | (bl << 16);
    const uint32_t ONE2 = 0x3F803F80u;
    const uint4 z4 = {0, 0, 0, 0};
    if (slot == 0) {
        uint4 a = {packn, ONE2, 0, 0};
        *(uint4*)(Na + (size_t)p * 16) = a;
    } else if (slot == 1) {
        *(uint4*)(Na + (size_t)p * 16 + 8) = z4;
    } else if (slot == 2) {
        uint4 bvec = {ONE2, packn, 0, 0};
        *(uint4*)(Nb + (size_t)p * 16) = bvec;
    } else if (slot == 3) {
        *(uint4*)(Nb + (size_t)p * 16 + 8) = z4;
    }
}

// ---------------------------------------------------------------------------
// Fused main: grid = B x 64 row-groups x 8 candidate-splits = 1024 blocks
// (4 blocks/CU). Block = 4 waves x 32 rows (32x32x16 MFMA), 1024 candidates.
// s computed entirely by MFMA (norm terms in a 5th K-step).
// Pass 1 (own chunks 0-3): 16 rotating bucket maxima -> tau = 10th largest
// of the 16 hi-merged maxima (exact underestimate of row's global 10th).
// Pass 2 (chunks 0-15): tau-seeded branchless stack; bitonic sort16+merge.
// Epilogue: last cs-block per rowgroup merges the 8 partial lists per row,
// computes S_n + rowgroup sum; last rowgroup does the final reduction.
// ---------------------------------------------------------------------------
__global__ __launch_bounds__(256, 4) void knn_main_kernel(const uint16_t* __restrict__ Xsw,
                                                          const uint16_t* __restrict__ Na,
                                                          const uint16_t* __restrict__ Nb,
                                                          float* __restrict__ part,
                                                          float* __restrict__ rgsum,
                                                          int* __restrict__ counters,
                                                          float* __restrict__ out) {
    __shared__ __align__(16) uint16_t tile[2][TILE_M * 64];  // 16 KB
    __shared__ __align__(16) uint16_t ext[2][TILE_M * 16];   // 4 KB
    __shared__ __align__(16) float stackm[C_ * 256];         // 16 KB
    __shared__ int flagA, flagB;

    const int tid = threadIdx.x;
    const int lane = tid & 63;
    const int wid = tid >> 6;
    const int hi = lane >> 5;
    const int c31 = lane & 31;
    const int blk = blockIdx.x;
    const int cs = blk & 7;
    const int rb = (blk >> 3) & 63;
    const int b = blk >> 9;
    const int nbase = rb * ROWS_PB;
    const int cbase = cs * CAND_PB;

    const int n_my = nbase + wid * 32 + c31;
    bf16x8 bfrag[4], bext;
    {
        const uint16_t* row = Xsw + ((size_t)(b * N_ + n_my)) * 64;
#pragma unroll
        for (int j = 0; j < 4; ++j) {
            const int slot = (2 * j + hi) ^ (n_my & 7);
            bfrag[j] = *(const bf16x8*)(row + slot * 8);
        }
        bext = *(const bf16x8*)(Nb + (size_t)(b * N_ + n_my) * 16 + hi * 8);
    }

    f32x16 zro;
#pragma unroll
    for (int i = 0; i < 16; ++i) zro[i] = 0.f;

    const char* gXc = (const char*)(Xsw + ((size_t)b * N_ + cbase) * 64);
    const char* gAc = (const char*)(Na + ((size_t)b * N_ + cbase) * 16);

    auto stage = [&](int buf, int ch) {
        const char* g = gXc + (size_t)ch * 8192 + wid * 2048 + lane * 16;
        char* l = (char*)&tile[buf][0] + wid * 2048;
        glds16(g, l);
        glds16(g + 1024, l + 1024);
        const char* ge = gAc + (size_t)ch * 2048 + wid * 512 + lane * 4;
        char* le = (char*)&ext[buf][0] + wid * 512;
        glds4(ge, le);
        glds4(ge + 256, le + 256);
    };

    // shared MFMA body: the 16 s-values for (chunk, subtile ms)
    auto mfma_sub = [&](const uint16_t* tl, const uint16_t* el, int ms) -> f32x16 {
        const int r_my = ms * 32 + c31;
        const bf16x8 ae = *(const bf16x8*)(el + r_my * 16 + hi * 8);
        f32x16 acc = __builtin_amdgcn_mfma_f32_32x32x16_bf16(ae, bext, zro, 0, 0, 0);
#pragma unroll
        for (int j = 0; j < 4; ++j) {
            const int slot = (2 * j + hi) ^ (r_my & 7);
            const bf16x8 a = *(const bf16x8*)(tl + r_my * 64 + slot * 8);
            acc = __builtin_amdgcn_mfma_f32_32x32x16_bf16(a, bfrag[j], acc, 0, 0, 0);
        }
        return acc;
    };

    // ---------------- pass 1: bucket maxima over sample chunks 0-3 ---------
    float bk[NBK];
#pragma unroll
    for (int j = 0; j < NBK; ++j) bk[j] = -INF_;

    stage(0, 0);
    __syncthreads();   // tile 0 ready

#pragma unroll 1
    for (int it = 0; it < SCH; ++it) {
        const int cur = it & 1;
        stage(cur ^ 1, (it + 1 < SCH) ? it + 1 : 0);   // it=3 restages chunk 0
        const int mg0 = cbase + it * TILE_M;
        const bool sf = (mg0 < nbase + ROWS_PB) && (mg0 + TILE_M > nbase);
        const uint16_t* tl = &tile[cur][0];
        const uint16_t* el = &ext[cur][0];
#pragma unroll
        for (int ms = 0; ms < 2; ++ms) {
            f32x16 acc = mfma_sub(tl, el, ms);
            if (sf) {
#pragma unroll
                for (int r = 0; r < 16; ++r) {
                    const int mg = mg0 + ms * 32 + (r & 3) + 8 * (r >> 2) + 4 * hi;
                    if (mg == n_my) acc[r] = -INF_;
                }
            }
#pragma unroll
            for (int r = 0; r < 16; ++r) bk[r] = fmaxf(bk[r], acc[r]);
        }
        __syncthreads();
    }

    // tau = 10th largest of 16 hi-merged bucket maxima (exact underestimate)
    float tau;
    {
        float v[NBK];
#pragma unroll
        for (int r = 0; r < NBK; ++r) v[r] = fmaxf(bk[r], __shfl_xor(bk[r], 32));
#pragma unroll
        for (int k = 2; k <= 16; k <<= 1) {
#pragma unroll
            for (int j = k >> 1; j > 0; j >>= 1) {
#pragma unroll
                for (int i2 = 0; i2 < 16; ++i2) {
                    const int ixj = i2 ^ j;
                    if (ixj > i2) {
                        const float a2 = v[i2], c2 = v[ixj];
                        const float mx = fmaxf(a2, c2), mn = fminf(a2, c2);
                        const bool up = ((i2 & k) == 0);
                        v[i2] = up ? mx : mn;
                        v[ixj] = up ? mn : mx;
                    }
                }
            }
        }
        tau = v[9];
    }

    float t[K_];                      // s-domain top-10, descending
#pragma unroll
    for (int j = 0; j < K_; ++j) t[j] = -INF_;
    int so = tid;                     // stack cursor; cnt = so >> 8

    // compaction: bitonic sort16 of stack (desc) + bitonic merge with t[10]
    auto compact_fn = [&]() {
        const int cnt = so >> 8;
        float v[16];
#pragma unroll
        for (int s = 0; s < C_; ++s) {
            const float q = stackm[s * 256 + tid];
            v[s] = (s < cnt) ? q : -INF_;
        }
#pragma unroll
        for (int k = 2; k <= 16; k <<= 1) {
#pragma unroll
            for (int j = k >> 1; j > 0; j >>= 1) {
#pragma unroll
                for (int i = 0; i < 16; ++i) {
                    const int ixj = i ^ j;
                    if (ixj > i) {
                        const float a = v[i], c = v[ixj];
                        const float mx = fmaxf(a, c), mn = fminf(a, c);
                        const bool up = ((i & k) == 0);
                        v[i] = up ? mx : mn;
                        v[ixj] = up ? mn : mx;
                    }
                }
            }
        }
        float L[16];
#pragma unroll
        for (int i = 0; i < 16; ++i) {
            const float ti = (i < K_) ? t[i] : -INF_;
            L[i] = fmaxf(ti, v[15 - i]);
        }
#pragma unroll
        for (int j = 8; j > 0; j >>= 1) {
#pragma unroll
            for (int i = 0; i < 16; ++i) {
                const int ixj = i ^ j;
                if (ixj > i) {
                    const float a = L[i], c = L[ixj];
                    L[i] = fmaxf(a, c);
                    L[ixj] = fminf(a, c);
                }
            }
        }
#pragma unroll
        for (int i = 0; i < K_; ++i) t[i] = L[i];
        tau = fmaxf(tau, t[K_ - 1]);   // monotone: never drop below seed
        so = tid;
    };

    // ---------------- pass 2: seeded selection over chunks 0-15 ------------
#pragma unroll 1
    for (int ch = 0; ch < NCH; ++ch) {
        const int cur = ch & 1;
        if (ch + 1 < NCH) stage(cur ^ 1, ch + 1);   // flies under compute
        const int mg0 = cbase + ch * TILE_M;
        const bool sf = (mg0 < nbase + ROWS_PB) && (mg0 + TILE_M > nbase);
        const uint16_t* tl = &tile[cur][0];
        const uint16_t* el = &ext[cur][0];

#pragma unroll
        for (int ms = 0; ms < 2; ++ms) {
            f32x16 acc = mfma_sub(tl, el, ms);
            if (sf) {
#pragma unroll
                for (int r = 0; r < 16; ++r) {
                    const int mg = mg0 + ms * 32 + (r & 3) + 8 * (r >> 2) + 4 * hi;
                    if (mg == n_my) acc[r] = -INF_;
                }
            }
#pragma unroll
            for (int r0 = 0; r0 < 16; r0 += 4) {
                if (__any((so >> 8) > C_ - 4)) compact_fn();
#pragma unroll
                for (int r = r0; r < r0 + 4; ++r) {
                    const float q = acc[r];
                    stackm[so] = q;
                    so += (q >= tau) ? 256 : 0;
                }
            }
        }
        __syncthreads();   // drains async stage + sync
    }
    compact_fn();          // final drain -> t[0..9] descending

    // in-block merge of the 2 hi-lane lists per row (stride-11: gcd(11,32)=1)
    __syncthreads();
    float* mb = (float*)&tile[0][0];    // 256 lists x 11 floats = 11264 B
    {
        float* my = mb + tid * 11;
#pragma unroll
        for (int j = 0; j < K_; ++j) my[j] = t[j];
    }
    __syncthreads();
    if (tid < 128) {
        const int w = tid >> 5, r = tid & 31;
        const float* la = mb + (w * 64 + r) * 11;
        const float* lb = mb + (w * 64 + 32 + r) * 11;
        float o[K_];
#pragma unroll
        for (int j = 0; j < K_; ++j) o[j] = la[j];
#pragma unroll
        for (int j = 0; j < K_; ++j) {
            const float q = lb[j];
            if (q > o[K_ - 1]) {
                o[K_ - 1] = q;
#pragma unroll
                for (int jj = K_ - 1; jj > 0; --jj) {
                    const float a = fmaxf(o[jj - 1], o[jj]);
                    const float bm = fminf(o[jj - 1], o[jj]);
                    o[jj - 1] = a;
                    o[jj] = bm;
                }
            }
        }
        float* dst = part + ((size_t)(b * N_ + nbase + w * 32 + r) * CSPLIT + cs) * K_;
#pragma unroll
        for (int j = 0; j < K_; ++j) dst[j] = -2.f * o[j];   // q = d^2, ascending
        __threadfence();                 // release this block's lists
    }
    __syncthreads();
    if (tid == 0)
        flagA = (atomicAdd(&counters[b * 64 + rb], 1) == CSPLIT - 1) ? 1 : 0;
    __syncthreads();
    if (!flagA) return;

    // ---- last cs-block of this rowgroup: merge 8 lists per row, S_n sum ---
    __threadfence();                     // acquire other blocks' lists
    float S = 0.f;
    if (tid < 128) {
        const volatile float* src =
            part + (size_t)(b * N_ + nbase + tid) * CSPLIT * K_;
        float tt[K_];
#pragma unroll
        for (int j = 0; j < K_; ++j) tt[j] = INF_;
        for (int c = 0; c < CSPLIT; ++c) {
            const volatile float* L = src + c * K_;
            for (int i = 0; i < K_; ++i) {       // list ascending: early exit
                const float q = L[i];
                if (!(q < tt[K_ - 1])) break;
                tt[K_ - 1] = q;
#pragma unroll
                for (int j = K_ - 1; j > 0; --j) {
                    const float lo = fminf(tt[j - 1], tt[j]);
                    const float hh = fmaxf(tt[j - 1], tt[j]);
                    tt[j - 1] = lo;
                    tt[j] = hh;
                }
            }
        }
        const float q9 = fmaxf(tt[K_ - 1], 1e-12f);
        S = 9.f * logf(q9);
#pragma unroll
        for (int j = 0; j < K_ - 1; ++j) S -= logf(fmaxf(tt[j], 1e-12f));
        S *= 0.5f;
    }
    float* red = (float*)stackm;
    if (tid < 128) red[tid] = S;
    __syncthreads();
    for (int off = 64; off > 0; off >>= 1) {
        if (tid < off) red[tid] += red[tid + off];
        __syncthreads();
    }
    if (tid == 0) {
        rgsum[b * 64 + rb] = red[0];
        __threadfence();                 // release rgsum
        flagB = (atomicAdd(&counters[128], 1) == 127) ? 1 : 0;
    }
    __syncthreads();
    if (flagB && tid < 128) {
        __threadfence();                 // acquire all rgsum
        // rgsum[0..63] = batch 0, [64..127] = batch 1; one load per lane,
        // fixed-order 64-lane butterfly per wave (deterministic)
        float v = ((volatile float*)rgsum)[tid];
        v += __shfl_xor(v, 1);
        v += __shfl_xor(v, 2);
        v += __shfl_xor(v, 4);
        v += __shfl_xor(v, 8);
        v += __shfl_xor(v, 16);
        v += __shfl_xor(v, 32);
        if (tid == 0) out[0] = 9.f * (float)N_ / v;
        if (tid == 64) out[1] = 9.f * (float)N_ / v;
    }
}

// ---------------------------------------------------------------------------
extern "C" void kernel_launch(void* const* d_in, const int* in_sizes, int n_in,
                              void* d_out, int out_size, void* d_ws, size_t ws_size,
                              hipStream_t stream) {
    const float* X = (const float*)d_in[0];
    float* out = (float*)d_out;

    // ws: Xsw (2 MB) | Na (512 KB) | Nb (512 KB) | part (5.24 MB) |
    //     rgsum (512 B) | counters (129 ints)
    uint16_t* Xsw = (uint16_t*)d_ws;
    uint16_t* Na = Xsw + (size_t)B_ * N_ * D_;
    uint16_t* Nb = Na + (size_t)B_ * N_ * 16;
    float* part = (float*)(Nb + (size_t)B_ * N_ * 16);
    float* rgsum = part + (size_t)B_ * N_ * CSPLIT * K_;
    int* counters = (int*)(rgsum + 128);

    prep_kernel<<<(B_ * N_ * 8) / 256, 256, 0, stream>>>(X, Xsw, Na, Nb, counters);
    knn_main_kernel<<<B_ * (N_ / ROWS_PB) * CSPLIT, 256, 0, stream>>>(
        Xsw, Na, Nb, part, rgsum, counters, out);
}

// Round 16
// 79.705 us; speedup vs baseline: 2.6632x; 2.6632x over previous
//
#include <hip/hip_runtime.h>
#include <math.h>
#include <stdint.h>

#define B_ 2
#define N_ 8192
#define D_ 64
#define K_ 10
#define CSPLIT 8                 // candidate-axis split
#define CAND_PB (N_ / CSPLIT)    // 1024 candidates per block
#define TILE_M 64                // candidates per chunk
#define NCH (CAND_PB / TILE_M)   // 16 chunks (pass 2)
#define SCH 4                    // pass-1 sample chunks (256 cands)
#define ROWS_PB 128              // 4 waves x 32 rows
#define C_ 16                    // per-lane survivor-stack capacity
#define NBK 16                   // pass-1 buckets
#define INF_ 3.4e38f

typedef __attribute__((ext_vector_type(8))) short bf16x8;
typedef __attribute__((ext_vector_type(16))) float f32x16;

// Async global->LDS DMA. LDS dest = wave-uniform base + lane*size (HW);
// global src is per-lane.
__device__ __forceinline__ void glds16(const void* g, void* l) {
    __builtin_amdgcn_global_load_lds(
        (const __attribute__((address_space(1))) unsigned int*)(uintptr_t)g,
        (__attribute__((address_space(3))) unsigned int*)(uint32_t)(uintptr_t)l,
        16, 0, 0);
}
__device__ __forceinline__ void glds4(const void* g, void* l) {
    __builtin_amdgcn_global_load_lds(
        (const __attribute__((address_space(1))) unsigned int*)(uintptr_t)g,
        (__attribute__((address_space(3))) unsigned int*)(uint32_t)(uintptr_t)l,
        4, 0, 0);
}

__device__ __forceinline__ uint32_t rne_bf16(float f) {
    uint32_t u = __float_as_uint(f);
    return ((u + 0x7FFFu + ((u >> 16) & 1u)) >> 16) & 0xFFFFu;
}

// ---------------------------------------------------------------------------
// Prep: f32 -> bf16 (RNE) with XOR slot-swizzle baked into the global layout;
// norm-extension rows Na (A-side: [-.5sq_hi, -.5sq_lo, 1, 1, 0..]) and
// Nb (B-side: [1, 1, -.5sq_hi, -.5sq_lo, 0..]), 16 halves each.
// Also zeroes the merge-completion counter.
// ---------------------------------------------------------------------------
__global__ __launch_bounds__(256) void prep_kernel(const float* __restrict__ X,
                                                   uint16_t* __restrict__ Xsw,
                                                   uint16_t* __restrict__ Na,
                                                   uint16_t* __restrict__ Nb,
                                                   int* __restrict__ counter) {
    const int id = blockIdx.x * 256 + threadIdx.x;   // 0 .. B*N*8-1
    if (id == 0) *counter = 0;
    const int p = id >> 3;                           // global point
    const int slot = id & 7;
    const float4* s4 = (const float4*)(X + (size_t)p * D_ + slot * 8);
    float4 va = s4[0], vb = s4[1];
    float v[8] = {va.x, va.y, va.z, va.w, vb.x, vb.y, vb.z, vb.w};
    uint32_t h[8];
    float ss = 0.f;
#pragma unroll
    for (int i = 0; i < 8; ++i) {
        uint32_t u = __float_as_uint(v[i]);
        uint32_t r = (u + 0x7FFFu + ((u >> 16) & 1u)) & 0xFFFF0000u;  // RNE
        h[i] = r >> 16;
        float rv = __uint_as_float(r);
        ss = fmaf(rv, rv, ss);
    }
    uint4 w;
    w.x = h[0] | (h[1] << 16);
    w.y = h[2] | (h[3] << 16);
    w.z = h[4] | (h[5] << 16);
    w.w = h[6] | (h[7] << 16);
    *(uint4*)(Xsw + (size_t)p * D_ + (size_t)((slot ^ (p & 7)) * 8)) = w;
    ss += __shfl_xor(ss, 1);
    ss += __shfl_xor(ss, 2);
    ss += __shfl_xor(ss, 4);

    const float hv = -0.5f * ss;
    const uint32_t bh = rne_bf16(hv);
    const float rem = hv - __uint_as_float(bh << 16);
    const uint32_t bl = rne_bf16(rem);
    const uint32_t packn = bh | (bl << 16);
    const uint32_t ONE2 = 0x3F803F80u;
    const uint4 z4 = {0, 0, 0, 0};
    if (slot == 0) {
        uint4 a = {packn, ONE2, 0, 0};
        *(uint4*)(Na + (size_t)p * 16) = a;
    } else if (slot == 1) {
        *(uint4*)(Na + (size_t)p * 16 + 8) = z4;
    } else if (slot == 2) {
        uint4 bvec = {ONE2, packn, 0, 0};
        *(uint4*)(Nb + (size_t)p * 16) = bvec;
    } else if (slot == 3) {
        *(uint4*)(Nb + (size_t)p * 16 + 8) = z4;
    }
}

// ---------------------------------------------------------------------------
// Fused main: grid = B x 64 row-groups x 8 candidate-splits = 1024 blocks
// (4 blocks/CU). Block = 4 waves x 32 rows (32x32x16 MFMA), 1024 candidates.
// s computed entirely by MFMA (norm terms in a 5th K-step).
// Pass 1 (own chunks 0-3): 16 rotating bucket maxima -> tau = 10th largest
// of the 16 hi-merged maxima (16 disjoint candidate groups => 10 distinct
// witnesses => exact underestimate of this row's global 10th-largest s).
// Pass 2 (chunks 0-15): tau-seeded branchless stack; bitonic sort16+merge
// compaction, tau monotonically raised. (r12-proven selection structure.)
// ---------------------------------------------------------------------------
__global__ __launch_bounds__(256, 4) void knn_main_kernel(const uint16_t* __restrict__ Xsw,
                                                          const uint16_t* __restrict__ Na,
                                                          const uint16_t* __restrict__ Nb,
                                                          float* __restrict__ part) {
    __shared__ __align__(16) uint16_t tile[2][TILE_M * 64];  // 16 KB
    __shared__ __align__(16) uint16_t ext[2][TILE_M * 16];   // 4 KB
    __shared__ __align__(16) float stackm[C_ * 256];         // 16 KB

    const int tid = threadIdx.x;
    const int lane = tid & 63;
    const int wid = tid >> 6;
    const int hi = lane >> 5;
    const int c31 = lane & 31;
    const int blk = blockIdx.x;
    const int cs = blk & 7;
    const int rb = (blk >> 3) & 63;
    const int b = blk >> 9;
    const int nbase = rb * ROWS_PB;
    const int cbase = cs * CAND_PB;

    const int n_my = nbase + wid * 32 + c31;
    bf16x8 bfrag[4], bext;
    {
        const uint16_t* row = Xsw + ((size_t)(b * N_ + n_my)) * 64;
#pragma unroll
        for (int j = 0; j < 4; ++j) {
            const int slot = (2 * j + hi) ^ (n_my & 7);
            bfrag[j] = *(const bf16x8*)(row + slot * 8);
        }
        bext = *(const bf16x8*)(Nb + (size_t)(b * N_ + n_my) * 16 + hi * 8);
    }

    f32x16 zro;
#pragma unroll
    for (int i = 0; i < 16; ++i) zro[i] = 0.f;

    const char* gXc = (const char*)(Xsw + ((size_t)b * N_ + cbase) * 64);
    const char* gAc = (const char*)(Na + ((size_t)b * N_ + cbase) * 16);

    auto stage = [&](int buf, int ch) {
        const char* g = gXc + (size_t)ch * 8192 + wid * 2048 + lane * 16;
        char* l = (char*)&tile[buf][0] + wid * 2048;
        glds16(g, l);
        glds16(g + 1024, l + 1024);
        const char* ge = gAc + (size_t)ch * 2048 + wid * 512 + lane * 4;
        char* le = (char*)&ext[buf][0] + wid * 512;
        glds4(ge, le);
        glds4(ge + 256, le + 256);
    };

    // shared MFMA body: returns the 16 s-values for (chunk base mg0, subtile ms)
    auto mfma_sub = [&](const uint16_t* tl, const uint16_t* el, int ms) -> f32x16 {
        const int r_my = ms * 32 + c31;
        const bf16x8 ae = *(const bf16x8*)(el + r_my * 16 + hi * 8);
        f32x16 acc = __builtin_amdgcn_mfma_f32_32x32x16_bf16(ae, bext, zro, 0, 0, 0);
#pragma unroll
        for (int j = 0; j < 4; ++j) {
            const int slot = (2 * j + hi) ^ (r_my & 7);
            const bf16x8 a = *(const bf16x8*)(tl + r_my * 64 + slot * 8);
            acc = __builtin_amdgcn_mfma_f32_32x32x16_bf16(a, bfrag[j], acc, 0, 0, 0);
        }
        return acc;
    };

    // ---------------- pass 1: bucket maxima over sample chunks 0-3 ---------
    float bk[NBK];
#pragma unroll
    for (int j = 0; j < NBK; ++j) bk[j] = -INF_;

    stage(0, 0);
    __syncthreads();   // tile 0 ready

#pragma unroll 1
    for (int it = 0; it < SCH; ++it) {
        const int cur = it & 1;
        stage(cur ^ 1, (it + 1 < SCH) ? it + 1 : 0);   // it=3 restages chunk 0
        const int mg0 = cbase + it * TILE_M;
        const bool sf = (mg0 < nbase + ROWS_PB) && (mg0 + TILE_M > nbase);
        const uint16_t* tl = &tile[cur][0];
        const uint16_t* el = &ext[cur][0];
#pragma unroll
        for (int ms = 0; ms < 2; ++ms) {
            f32x16 acc = mfma_sub(tl, el, ms);
            if (sf) {
#pragma unroll
                for (int r = 0; r < 16; ++r) {
                    const int mg = mg0 + ms * 32 + (r & 3) + 8 * (r >> 2) + 4 * hi;
                    if (mg == n_my) acc[r] = -INF_;
                }
            }
#pragma unroll
            for (int r = 0; r < 16; ++r) bk[r] = fmaxf(bk[r], acc[r]);
        }
        __syncthreads();
    }

    // tau = 10th largest of 16 hi-merged bucket maxima (exact underestimate)
    float tau;
    {
        float v[NBK];
#pragma unroll
        for (int r = 0; r < NBK; ++r) v[r] = fmaxf(bk[r], __shfl_xor(bk[r], 32));
#pragma unroll
        for (int k = 2; k <= 16; k <<= 1) {
#pragma unroll
            for (int j = k >> 1; j > 0; j >>= 1) {
#pragma unroll
                for (int i2 = 0; i2 < 16; ++i2) {
                    const int ixj = i2 ^ j;
                    if (ixj > i2) {
                        const float a2 = v[i2], c2 = v[ixj];
                        const float mx = fmaxf(a2, c2), mn = fminf(a2, c2);
                        const bool up = ((i2 & k) == 0);
                        v[i2] = up ? mx : mn;
                        v[ixj] = up ? mn : mx;
                    }
                }
            }
        }
        tau = v[9];
    }

    float t[K_];                      // s-domain top-10, descending
#pragma unroll
    for (int j = 0; j < K_; ++j) t[j] = -INF_;
    int so = tid;                     // stack cursor; cnt = so >> 8

    // compaction: bitonic sort16 of stack (desc) + bitonic merge with t[10]
    auto compact_fn = [&]() {
        const int cnt = so >> 8;
        float v[16];
#pragma unroll
        for (int s = 0; s < C_; ++s) {
            const float q = stackm[s * 256 + tid];
            v[s] = (s < cnt) ? q : -INF_;
        }
#pragma unroll
        for (int k = 2; k <= 16; k <<= 1) {
#pragma unroll
            for (int j = k >> 1; j > 0; j >>= 1) {
#pragma unroll
                for (int i = 0; i < 16; ++i) {
                    const int ixj = i ^ j;
                    if (ixj > i) {
                        const float a = v[i], c = v[ixj];
                        const float mx = fmaxf(a, c), mn = fminf(a, c);
                        const bool up = ((i & k) == 0);
                        v[i] = up ? mx : mn;
                        v[ixj] = up ? mn : mx;
                    }
                }
            }
        }
        float L[16];
#pragma unroll
        for (int i = 0; i < 16; ++i) {
            const float ti = (i < K_) ? t[i] : -INF_;
            L[i] = fmaxf(ti, v[15 - i]);
        }
#pragma unroll
        for (int j = 8; j > 0; j >>= 1) {
#pragma unroll
            for (int i = 0; i < 16; ++i) {
                const int ixj = i ^ j;
                if (ixj > i) {
                    const float a = L[i], c = L[ixj];
                    L[i] = fmaxf(a, c);
                    L[ixj] = fminf(a, c);
                }
            }
        }
#pragma unroll
        for (int i = 0; i < K_; ++i) t[i] = L[i];
        tau = fmaxf(tau, t[K_ - 1]);   // monotone: never drop below seed
        so = tid;
    };

    // ---------------- pass 2: seeded selection over chunks 0-15 ------------
    // buffer parity continues: chunk 0 is in tile[0] (restaged at it=3)
#pragma unroll 1
    for (int ch = 0; ch < NCH; ++ch) {
        const int cur = ch & 1;
        if (ch + 1 < NCH) stage(cur ^ 1, ch + 1);   // flies under compute
        const int mg0 = cbase + ch * TILE_M;
        const bool sf = (mg0 < nbase + ROWS_PB) && (mg0 + TILE_M > nbase);
        const uint16_t* tl = &tile[cur][0];
        const uint16_t* el = &ext[cur][0];

#pragma unroll
        for (int ms = 0; ms < 2; ++ms) {
            f32x16 acc = mfma_sub(tl, el, ms);
            if (sf) {
#pragma unroll
                for (int r = 0; r < 16; ++r) {
                    const int mg = mg0 + ms * 32 + (r & 3) + 8 * (r >> 2) + 4 * hi;
                    if (mg == n_my) acc[r] = -INF_;
                }
            }
            // branchless pushes (rare with seeded tau); gate every 4
#pragma unroll
            for (int r0 = 0; r0 < 16; r0 += 4) {
                if (__any((so >> 8) > C_ - 4)) compact_fn();
#pragma unroll
                for (int r = r0; r < r0 + 4; ++r) {
                    const float q = acc[r];
                    stackm[so] = q;
                    so += (q >= tau) ? 256 : 0;
                }
            }
        }
        __syncthreads();   // drains async stage + sync
    }
    compact_fn();          // final drain -> t[0..9] descending

    // in-block merge of the 2 hi-lane lists per row (stride-11: gcd(11,32)=1)
    __syncthreads();
    float* mb = (float*)&tile[0][0];    // 256 lists x 11 floats = 11264 B
    {
        float* my = mb + tid * 11;
#pragma unroll
        for (int j = 0; j < K_; ++j) my[j] = t[j];
    }
    __syncthreads();
    if (tid < 128) {
        const int w = tid >> 5, r = tid & 31;
        const float* la = mb + (w * 64 + r) * 11;
        const float* lb = mb + (w * 64 + 32 + r) * 11;
        float o[K_];
#pragma unroll
        for (int j = 0; j < K_; ++j) o[j] = la[j];
#pragma unroll
        for (int j = 0; j < K_; ++j) {
            const float q = lb[j];
            if (q > o[K_ - 1]) {
                o[K_ - 1] = q;
#pragma unroll
                for (int jj = K_ - 1; jj > 0; --jj) {
                    const float a = fmaxf(o[jj - 1], o[jj]);
                    const float bm = fminf(o[jj - 1], o[jj]);
                    o[jj - 1] = a;
                    o[jj] = bm;
                }
            }
        }
        float* dst = part + ((size_t)(b * N_ + nbase + w * 32 + r) * CSPLIT + cs) * K_;
#pragma unroll
        for (int j = 0; j < K_; ++j) dst[j] = -2.f * o[j];   // back to q = d^2
    }
}

// ---------------------------------------------------------------------------
// Merge: 64 blocks x 256 threads. Per point: select K smallest over CSPLIT
// ascending f32 lists (early-exit per list), S_n via logs, LDS tree-reduce.
// Last finishing block does the final sum with parallel lane reads + fixed-
// order butterfly. Deterministic.
// ---------------------------------------------------------------------------
__global__ __launch_bounds__(256) void merge_kernel(const float* __restrict__ part,
                                                    float* __restrict__ bsum,
                                                    int* __restrict__ counter,
                                                    float* __restrict__ out) {
    __shared__ float red[256];
    __shared__ int lastFlag;
    const int tid = threadIdx.x;
    const int p = blockIdx.x * 256 + tid;        // 0 .. B*N-1
    const float* src = part + (size_t)p * CSPLIT * K_;

    float t[K_];
#pragma unroll
    for (int j = 0; j < K_; ++j) t[j] = INF_;
    for (int c = 0; c < CSPLIT; ++c) {
        const float* L = src + c * K_;
        for (int i = 0; i < K_; ++i) {            // list ascending: early exit
            const float q = L[i];
            if (!(q < t[K_ - 1])) break;
            t[K_ - 1] = q;
#pragma unroll
            for (int j = K_ - 1; j > 0; --j) {
                const float lo = fminf(t[j - 1], t[j]);
                const float hh = fmaxf(t[j - 1], t[j]);
                t[j - 1] = lo;
                t[j] = hh;
            }
        }
    }

    const float q9 = fmaxf(t[K_ - 1], 1e-12f);
    float S = 9.f * logf(q9);
#pragma unroll
    for (int j = 0; j < K_ - 1; ++j) S -= logf(fmaxf(t[j], 1e-12f));
    S *= 0.5f;

    red[tid] = S;
    __syncthreads();
    for (int off = 128; off > 0; off >>= 1) {
        if (tid < off) red[tid] += red[tid + off];
        __syncthreads();
    }
    if (tid == 0) {
        bsum[blockIdx.x] = red[0];
        __threadfence();                              // release bsum
        lastFlag = (atomicAdd(counter, 1) == 63) ? 1 : 0;
    }
    __syncthreads();
    if (lastFlag && tid < 64) {
        __threadfence();                              // acquire others' bsum
        // blocks 0-31 cover batch 0 (points 0..8191), 32-63 batch 1
        float v = ((volatile float*)bsum)[tid];       // ONE load per lane
        v += __shfl_xor(v, 1);
        v += __shfl_xor(v, 2);
        v += __shfl_xor(v, 4);
        v += __shfl_xor(v, 8);
        v += __shfl_xor(v, 16);                       // sum within 32-half
        if (tid == 0) out[0] = 9.f * (float)N_ / v;
        if (tid == 32) out[1] = 9.f * (float)N_ / v;
    }
}

// ---------------------------------------------------------------------------
extern "C" void kernel_launch(void* const* d_in, const int* in_sizes, int n_in,
                              void* d_out, int out_size, void* d_ws, size_t ws_size,
                              hipStream_t stream) {
    const float* X = (const float*)d_in[0];
    float* out = (float*)d_out;

    // ws: Xsw (2 MB) | Na (512 KB) | Nb (512 KB) | part (5.24 MB) |
    //     bsum (256 B) | counter
    uint16_t* Xsw = (uint16_t*)d_ws;
    uint16_t* Na = Xsw + (size_t)B_ * N_ * D_;
    uint16_t* Nb = Na + (size_t)B_ * N_ * 16;
    float* part = (float*)(Nb + (size_t)B_ * N_ * 16);
    float* bsum = part + (size_t)B_ * N_ * CSPLIT * K_;
    int* counter = (int*)(bsum + 64);

    prep_kernel<<<(B_ * N_ * 8) / 256, 256, 0, stream>>>(X, Xsw, Na, Nb, counter);
    knn_main_kernel<<<B_ * (N_ / ROWS_PB) * CSPLIT, 256, 0, stream>>>(Xsw, Na, Nb, part);
    merge_kernel<<<(B_ * N_) / 256, 256, 0, stream>>>(part, bsum, counter, out);
}